// Round 10
// baseline (134.615 us; speedup 1.0000x reference)
//
#include <hip/hip_runtime.h>
#include <hip/hip_bf16.h>
#include <math.h>

typedef _Float16 f16x8 __attribute__((ext_vector_type(8)));
typedef _Float16 f16x4 __attribute__((ext_vector_type(4)));
typedef float f32x4 __attribute__((ext_vector_type(4)));
typedef float f32x16 __attribute__((ext_vector_type(16)));

#define LDH 264  // 256 + 8 f16 pad (528B row stride, 16B-aligned rows)

// ---------------- fused prep ----------------------------------------------------
// blocks 0..23: W2/W3/W4 -> f16 fragment-contiguous 32x32 layout, LDS-staged:
//   frag = (L*8+cg)*16+ks ; col = cg*32+(l&31) ; k = ks*16+(l>>5)*8+e
// blocks 24..183: A/B projection (f16 output, b1 folded into A)
__global__ void prep(const float* __restrict__ x, const float* __restrict__ W1,
                     const float* __restrict__ b1,
                     const float* __restrict__ W2, const float* __restrict__ W3,
                     const float* __restrict__ W4,
                     _Float16* __restrict__ A, _Float16* __restrict__ B,
                     _Float16* __restrict__ Wt) {
    if (blockIdx.x < 24) {
        __shared__ _Float16 ws[256 * 33];      // [k][c], pad 33
        int L = blockIdx.x >> 3, cg = blockIdx.x & 7;
        const float* W = (L == 0) ? W2 : (L == 1) ? W3 : W4;
        int t = threadIdx.x;
        for (int i = t; i < 8192; i += 512) {
            int k = i >> 5, c = i & 31;
            ws[k * 33 + c] = (_Float16)W[k * 256 + cg * 32 + c];
        }
        __syncthreads();
        int l = t >> 3, e = t & 7;
        int c = l & 31, kb = (l >> 5) * 8 + e;
        _Float16* dst = Wt + (size_t)((L * 8 + cg) * 16) * 512 + t;
#pragma unroll
        for (int ks = 0; ks < 16; ks++)
            dst[ks * 512] = ws[(ks * 16 + kb) * 33 + c];
        return;
    }
    __shared__ float xs[258 * 4];
    int blk = blockIdx.x - 24;
    int bs = blk >> 2, pg = blk & 3;           // 4 p-values per block
    for (int i = threadIdx.x; i < 1024; i += 512) {
        int c = i >> 2, pp = i & 3;
        xs[i] = x[bs * 4096 + c * 16 + pg * 4 + pp];
    }
    if (threadIdx.x < 8) {
        int pp = threadIdx.x & 3, c = 256 + (threadIdx.x >> 2);
        int p = pg * 4 + pp;
        xs[c * 4 + pp] = (float)((c == 256) ? (p >> 2) : (p & 3)) * 0.25f;
    }
    __syncthreads();
    int half = threadIdx.x >> 8;               // 0 -> A, 1 -> B
    int col  = threadIdx.x & 255;
    float acc[4] = {0.f, 0.f, 0.f, 0.f};
    const float* Wp = W1 + half * 258 * 256 + col;
#pragma unroll 1
    for (int c0 = 0; c0 < 256; c0 += 8) {
        float w[8];
#pragma unroll
        for (int j = 0; j < 8; j++) w[j] = Wp[(c0 + j) * 256];
#pragma unroll
        for (int j = 0; j < 8; j++)
#pragma unroll
            for (int pp = 0; pp < 4; pp++) acc[pp] += xs[(c0 + j) * 4 + pp] * w[j];
    }
#pragma unroll
    for (int c = 256; c < 258; c++) {
        float w = Wp[c * 256];
#pragma unroll
        for (int pp = 0; pp < 4; pp++) acc[pp] += xs[c * 4 + pp] * w;
    }
    _Float16* out = half ? B : A;
    float bias = half ? 0.f : b1[col];         // fold b1 into A once
#pragma unroll
    for (int pp = 0; pp < 4; pp++)
        out[(bs * 16 + pg * 4 + pp) * 256 + col] = (_Float16)(acc[pp] + bias);
}

// ---------------- the big fused kernel ------------------------------------------
// grid 3200 = (b,s1,s2) x 4 row-quarters; 256 threads = 4 waves, each 64r x 64c
// as 2x2 mfma_f32_32x32x16_f16 (plain loads). Bias pre-loaded into acc.
// LDS 33.8 KB -> 3 blocks/CU at (256,3); 170-reg budget avoids R7's spill.
__global__ __launch_bounds__(256, 3) void pairnet(
        const _Float16* __restrict__ A, const _Float16* __restrict__ B,
        const _Float16* __restrict__ Wt,
        const float* __restrict__ b2, const float* __restrict__ b3,
        const float* __restrict__ b4, float* __restrict__ pooled4) {
    __shared__ _Float16 hb[64 * LDH];          // 33.8 KB

    int blk = blockIdx.x;
    int qtr = blk & 3;
    int bss = blk >> 2;                        // (b*20+s1)*20+s2
    int s2  = bss % 20;
    int s1  = (bss / 20) % 20;
    int b   = bss / 400;
    int tid = threadIdx.x;

    // ---- layer 1: h1 = relu(A[b,s2,p2] + B[b,s1,p1]), packed f16 ----
    const _Float16* Abase = A + (b * 20 + s2) * 16 * 256;
    const _Float16* Bbase = B + ((b * 20 + s1) * 16 + qtr * 4) * 256;
#pragma unroll
    for (int it = 0; it < 8; it++) {
        int u = it * 256 + tid;            // 0..2047 8-col units
        int r = u >> 5;                    // row 0..63 (= p1loc*16 + p2)
        int c = (u & 31) * 8;              // col
        f16x8 av = *(const f16x8*)(Abase + (r & 15) * 256 + c);
        f16x8 bv = *(const f16x8*)(Bbase + (r >> 4) * 256 + c);
        f16x8 hv = av + bv;
#pragma unroll
        for (int j = 0; j < 8; j++)
            hv[j] = hv[j] > (_Float16)0.f ? hv[j] : (_Float16)0.f;
        *(f16x8*)(hb + r * LDH + c) = hv;
    }

    int wid = tid >> 6, lane = tid & 63;
    int col0 = wid * 64;                   // wave owns 64 cols x all 64 rows
    int cg0  = wid * 2;                    // two 32-col fragment groups
    int l31 = lane & 31, hi = lane >> 5;

    const _Float16* abase = hb + l31 * LDH + hi * 8;

    // prefetch L=0 ks=0 W frags (global, overlaps with build barrier)
    const _Float16* wb0 = Wt + (size_t)(cg0 * 16) * 512 + lane * 8;
    f16x8 pw0 = *(const f16x8*)(wb0);
    f16x8 pw1 = *(const f16x8*)(wb0 + 16 * 512);
    __syncthreads();

#pragma unroll
    for (int L = 0; L < 3; L++) {
        const float* bias = (L == 0) ? b2 : (L == 1) ? b3 : b4;
        const _Float16* wb = Wt + (size_t)((L * 8 + cg0) * 16) * 512 + lane * 8;

        // bias-init accumulators (replaces zero-init; epilogue add eliminated)
        f32x16 acc00, acc01, acc10, acc11;
#pragma unroll
        for (int q = 0; q < 4; q++) {
            float4 bv0 = *(const float4*)(bias + col0 + 8 * q + 4 * hi);
            float4 bv1 = *(const float4*)(bias + col0 + 32 + 8 * q + 4 * hi);
#pragma unroll
            for (int j = 0; j < 4; j++) {
                float e0 = j == 0 ? bv0.x : j == 1 ? bv0.y : j == 2 ? bv0.z : bv0.w;
                float e1 = j == 0 ? bv1.x : j == 1 ? bv1.y : j == 2 ? bv1.z : bv1.w;
                acc00[4 * q + j] = e0; acc10[4 * q + j] = e0;
                acc01[4 * q + j] = e1; acc11[4 * q + j] = e1;
            }
        }

#pragma unroll
        for (int ks = 0; ks < 16; ks++) {
            f16x8 w0 = (ks == 0) ? pw0 : *(const f16x8*)(wb + ks * 512);
            f16x8 w1 = (ks == 0) ? pw1 : *(const f16x8*)(wb + (16 + ks) * 512);
            f16x8 a0 = *(const f16x8*)(abase + ks * 16);
            f16x8 a1 = *(const f16x8*)(abase + 32 * LDH + ks * 16);
            // swapped operands -> D^T: reg r of acc(mi,ni):
            // row = 32*mi+l31, col = col0+32*ni+8*(r>>2)+4*hi+(r&3)
            acc00 = __builtin_amdgcn_mfma_f32_32x32x16_f16(w0, a0, acc00, 0, 0, 0);
            acc01 = __builtin_amdgcn_mfma_f32_32x32x16_f16(w1, a0, acc01, 0, 0, 0);
            acc10 = __builtin_amdgcn_mfma_f32_32x32x16_f16(w0, a1, acc10, 0, 0, 0);
            acc11 = __builtin_amdgcn_mfma_f32_32x32x16_f16(w1, a1, acc11, 0, 0, 0);
        }

        if (L < 2) {
            // prefetch next layer's ks=0 W frags BEFORE the barrier (pure
            // global loads, no LDS dependency -> overlap with barrier drain)
            const _Float16* wbN =
                Wt + (size_t)(((L + 1) * 8 + cg0) * 16) * 512 + lane * 8;
            pw0 = *(const f16x8*)(wbN);
            pw1 = *(const f16x8*)(wbN + 16 * 512);
            __syncthreads();               // all reads of hb complete
#pragma unroll
            for (int ni = 0; ni < 2; ni++) {
                const f32x16& aN0 = ni ? acc01 : acc00;
                const f32x16& aN1 = ni ? acc11 : acc10;
#pragma unroll
                for (int q = 0; q < 4; q++) {
                    int cb = col0 + 32 * ni + 8 * q + 4 * hi;
                    f16x4 h0, h1;
                    h0[0] = (_Float16)fmaxf(aN0[4 * q + 0], 0.f);
                    h0[1] = (_Float16)fmaxf(aN0[4 * q + 1], 0.f);
                    h0[2] = (_Float16)fmaxf(aN0[4 * q + 2], 0.f);
                    h0[3] = (_Float16)fmaxf(aN0[4 * q + 3], 0.f);
                    h1[0] = (_Float16)fmaxf(aN1[4 * q + 0], 0.f);
                    h1[1] = (_Float16)fmaxf(aN1[4 * q + 1], 0.f);
                    h1[2] = (_Float16)fmaxf(aN1[4 * q + 2], 0.f);
                    h1[3] = (_Float16)fmaxf(aN1[4 * q + 3], 0.f);
                    *(f16x4*)(hb + l31 * LDH + cb) = h0;
                    *(f16x4*)(hb + (32 + l31) * LDH + cb) = h1;
                }
            }
            __syncthreads();               // writes visible
        } else {
            // layer 4: relu (bias already in acc), pool 64 rows
#pragma unroll
            for (int ni = 0; ni < 2; ni++) {
                const f32x16& aN0 = ni ? acc01 : acc00;
                const f32x16& aN1 = ni ? acc11 : acc10;
                float s[16];
#pragma unroll
                for (int q = 0; q < 4; q++) {
#pragma unroll
                    for (int j = 0; j < 4; j++)
                        s[4 * q + j] = fmaxf(aN0[4 * q + j], 0.f) +
                                       fmaxf(aN1[4 * q + j], 0.f);
                }
#pragma unroll
                for (int mask = 1; mask <= 16; mask <<= 1)
#pragma unroll
                    for (int r = 0; r < 16; r++) s[r] += __shfl_xor(s[r], mask);
                if (l31 == 0) {
                    float* pp = pooled4 + ((size_t)qtr * 800 + bss) * 256;
#pragma unroll
                    for (int q = 0; q < 4; q++) {
                        float4 sv;
                        sv.x = s[4 * q + 0]; sv.y = s[4 * q + 1];
                        sv.z = s[4 * q + 2]; sv.w = s[4 * q + 3];
                        *(float4*)(pp + col0 + 32 * ni + 8 * q + 4 * hi) = sv;
                    }
                }
            }
        }
    }
}

// ---------------- final MLP on pooled [800,256] (sums 4 slabs) ------------------
__global__ void final_mlp(const float* __restrict__ pooled4,
        const float* __restrict__ Wf1, const float* __restrict__ bf1,
        const float* __restrict__ Wf2, const float* __restrict__ bf2,
        const float* __restrict__ Wf3, const float* __restrict__ bf3,
        const float* __restrict__ Wf4, const float* __restrict__ bf4,
        float* __restrict__ out) {
    __shared__ float p[4][256], y[4][256], z[4][256], y3[4][29];
    int r0 = blockIdx.x * 4;
    int t  = threadIdx.x;
    for (int i = t; i < 1024; i += 256) {
        int r = i >> 8, c = i & 255;
        float v = 0.f;
#pragma unroll
        for (int q = 0; q < 4; q++)
            v += pooled4[((size_t)q * 800 + r0 + r) * 256 + c];
        p[r][c] = v;
    }
    __syncthreads();
    float acc[4];
#pragma unroll
    for (int r = 0; r < 4; r++) acc[r] = bf1[t];
#pragma unroll 1
    for (int k0 = 0; k0 < 256; k0 += 8) {
        float w[8];
#pragma unroll
        for (int j = 0; j < 8; j++) w[j] = Wf1[(k0 + j) * 256 + t];
#pragma unroll
        for (int j = 0; j < 8; j++)
#pragma unroll
            for (int r = 0; r < 4; r++) acc[r] += p[r][k0 + j] * w[j];
    }
#pragma unroll
    for (int r = 0; r < 4; r++) y[r][t] = fmaxf(acc[r], 0.f);
    __syncthreads();
#pragma unroll
    for (int r = 0; r < 4; r++) acc[r] = bf2[t];
#pragma unroll 1
    for (int k0 = 0; k0 < 256; k0 += 8) {
        float w[8];
#pragma unroll
        for (int j = 0; j < 8; j++) w[j] = Wf2[(k0 + j) * 256 + t];
#pragma unroll
        for (int j = 0; j < 8; j++)
#pragma unroll
            for (int r = 0; r < 4; r++) acc[r] += y[r][k0 + j] * w[j];
    }
#pragma unroll
    for (int r = 0; r < 4; r++) z[r][t] = fmaxf(acc[r], 0.f);
    __syncthreads();
    if (t < 116) {
        int r = t / 29, c = t % 29;
        float a = bf3[c];
#pragma unroll 1
        for (int k0 = 0; k0 < 256; k0 += 8) {
            float w[8];
#pragma unroll
            for (int j = 0; j < 8; j++) w[j] = Wf3[(k0 + j) * 29 + c];
#pragma unroll
            for (int j = 0; j < 8; j++) a += z[r][k0 + j] * w[j];
        }
        y3[r][c] = fmaxf(a, 0.f);
    }
    __syncthreads();
    if (t < 4) {
        float zz = bf4[0];
#pragma unroll
        for (int c = 0; c < 29; c++) zz += y3[t][c] * Wf4[c];
        out[r0 + t] = 1.f / (1.f + expf(-zz));
    }
}

extern "C" void kernel_launch(void* const* d_in, const int* in_sizes, int n_in,
                              void* d_out, int out_size, void* d_ws, size_t ws_size,
                              hipStream_t stream) {
    const float* x   = (const float*)d_in[0];
    const float* W1  = (const float*)d_in[1];
    const float* b1  = (const float*)d_in[2];
    const float* W2  = (const float*)d_in[3];
    const float* b2  = (const float*)d_in[4];
    const float* W3  = (const float*)d_in[5];
    const float* b3  = (const float*)d_in[6];
    const float* W4  = (const float*)d_in[7];
    const float* b4  = (const float*)d_in[8];
    const float* Wf1 = (const float*)d_in[9];
    const float* bf1 = (const float*)d_in[10];
    const float* Wf2 = (const float*)d_in[11];
    const float* bf2 = (const float*)d_in[12];
    const float* Wf3 = (const float*)d_in[13];
    const float* bf3 = (const float*)d_in[14];
    const float* Wf4 = (const float*)d_in[15];
    const float* bf4 = (const float*)d_in[16];

    float* pooled4 = (float*)d_ws;                     // 4*800*256 f32
    _Float16* A    = (_Float16*)(pooled4 + 4 * 800 * 256); // 640*256 f16
    _Float16* Bp   = A + 640 * 256;                    // 640*256 f16
    _Float16* Wt   = Bp + 640 * 256;                   // 384 frags * 512 f16

    prep<<<184, 512, 0, stream>>>(x, W1, b1, W2, W3, W4, A, Bp, Wt);
    pairnet<<<3200, 256, 0, stream>>>(A, Bp, Wt, b2, b3, b4, pooled4);
    final_mlp<<<200, 256, 0, stream>>>(pooled4, Wf1, bf1, Wf2, bf2, Wf3, bf3, Wf4, bf4,
                                       (float*)d_out);
}